// Round 15
// baseline (134.072 us; speedup 1.0000x reference)
//
#include <hip/hip_runtime.h>
#include <hip/hip_fp16.h>

#define HP 192
#define WP 192
#define NPIX (HP * WP)   // 36864
#define SG 24
#define KSTRU 72         // smK/smV row stride in ushorts (f16): 144 B
#define PI_STRU 12       // smpi16 row stride in uints: 48 B
#define PRE16 33         // preLds16 row stride in uints (f16 pairs)

typedef _Float16 h2 __attribute__((ext_vector_type(2)));

__device__ __forceinline__ unsigned int h2pack(float a, float b) {
  h2 r;
  r[0] = (_Float16)a;
  r[1] = (_Float16)b;
  return __builtin_bit_cast(unsigned int, r);
}
__device__ __forceinline__ h2 ash2(unsigned int u) {
  return __builtin_bit_cast(h2, u);
}

// ---------------- Kernel 1: QKV projection (x read ONCE, staged in LDS) ------
// grid 576, block 256 = 64 px x 4 waves. Wave wv owns cols [wv*48, wv*48+48):
// weights are wave-uniform -> s_load. x staged as f16 pairs (9.2 KB LDS).
__global__ __launch_bounds__(256) void qkv_kernel(
    const float* __restrict__ x, const float* __restrict__ w_qk,
    const float* __restrict__ w_v, unsigned int* __restrict__ qb16,
    unsigned int* __restrict__ kb16, unsigned int* __restrict__ vb16) {
  __shared__ __align__(16) unsigned int xh[64 * 36];  // [px][32 pairs] pad 36
  const int tid = threadIdx.x;
  const int px0 = blockIdx.x * 64;
  // stage x: 64 px x 32 ch-pairs (global reads coalesced over px)
  for (int i = tid; i < 64 * 32; i += 256) {
    const int px = i & 63, cp = i >> 6;
    const float a = x[(2 * cp) * NPIX + px0 + px];
    const float b = x[(2 * cp + 1) * NPIX + px0 + px];
    xh[px * 36 + cp] = h2pack(a, b);
  }
  __syncthreads();

  const int lane = tid & 63;
  const int wv = __builtin_amdgcn_readfirstlane(tid >> 6);  // wave-uniform
  const int pix = px0 + lane;
  const unsigned int* xrow = xh + lane * 36;
  const uint4 xA = *(const uint4*)(xrow + 0);
  const uint4 xB = *(const uint4*)(xrow + 4);
  const uint4 xC = *(const uint4*)(xrow + 8);
  const uint4 xD = *(const uint4*)(xrow + 12);
  const uint4 xE = *(const uint4*)(xrow + 16);
  const uint4 xF = *(const uint4*)(xrow + 20);
  const uint4 xG = *(const uint4*)(xrow + 24);
  const uint4 xH = *(const uint4*)(xrow + 28);
  const float qscale = 0.25f * 1.44269504089f;  // hd^-0.5 * log2(e)

#pragma unroll 1
  for (int jg = 0; jg < 6; ++jg) {
    const int col = wv * 48 + jg * 8;  // wave-uniform
    float acc[8];
#pragma unroll
    for (int j = 0; j < 8; ++j) acc[j] = 0.f;
    const float* wbase;
    int wstride, wcol;
    if (col < 128) {
      wbase = w_qk; wstride = 128; wcol = col;
    } else {
      wbase = w_v; wstride = 64; wcol = col - 128;
    }
#define QKV_CH(XU, C0)                                                    \
    {                                                                     \
      const h2 ha = ash2((XU).x), hb = ash2((XU).y);                      \
      const h2 hc = ash2((XU).z), hd = ash2((XU).w);                      \
      const float* r0 = wbase + (C0 + 0) * wstride + wcol;                \
      const float* r1 = wbase + (C0 + 1) * wstride + wcol;                \
      const float* r2 = wbase + (C0 + 2) * wstride + wcol;                \
      const float* r3 = wbase + (C0 + 3) * wstride + wcol;                \
      const float* r4 = wbase + (C0 + 4) * wstride + wcol;                \
      const float* r5 = wbase + (C0 + 5) * wstride + wcol;                \
      const float* r6 = wbase + (C0 + 6) * wstride + wcol;                \
      const float* r7 = wbase + (C0 + 7) * wstride + wcol;                \
      _Pragma("unroll")                                                   \
      for (int j = 0; j < 8; ++j) {                                       \
        acc[j] = fmaf((float)ha[0], r0[j], acc[j]);                       \
        acc[j] = fmaf((float)ha[1], r1[j], acc[j]);                       \
        acc[j] = fmaf((float)hb[0], r2[j], acc[j]);                       \
        acc[j] = fmaf((float)hb[1], r3[j], acc[j]);                       \
        acc[j] = fmaf((float)hc[0], r4[j], acc[j]);                       \
        acc[j] = fmaf((float)hc[1], r5[j], acc[j]);                       \
        acc[j] = fmaf((float)hd[0], r6[j], acc[j]);                       \
        acc[j] = fmaf((float)hd[1], r7[j], acc[j]);                       \
      }                                                                   \
    }
    QKV_CH(xA, 0) QKV_CH(xB, 8) QKV_CH(xC, 16) QKV_CH(xD, 24)
    QKV_CH(xE, 32) QKV_CH(xF, 40) QKV_CH(xG, 48) QKV_CH(xH, 56)
#undef QKV_CH
    unsigned int* dst;
    float mul = 1.0f;
    if (col < 64) {
      dst = qb16 + (size_t)pix * 32 + (col >> 1);
      mul = qscale;
    } else if (col < 128) {
      dst = kb16 + (size_t)pix * 32 + ((col - 64) >> 1);
    } else {
      dst = vb16 + (size_t)pix * 32 + ((col - 128) >> 1);
    }
    uint4 o;
    o.x = h2pack(acc[0] * mul, acc[1] * mul);
    o.y = h2pack(acc[2] * mul, acc[3] * mul);
    o.z = h2pack(acc[4] * mul, acc[5] * mul);
    o.w = h2pack(acc[6] * mul, acc[7] * mul);
    *(uint4*)dst = o;
  }
}

__device__ __forceinline__ float pi_val(const float* __restrict__ sims, int th,
                                        int tw, int r, int c, int s) {
  const int dh = s / 3, dw = s - dh * 3;
  const int shi = th + dh - 1, swj = tw + dw - 1;
  if (shi < 0 || shi >= SG || swj < 0 || swj >= SG || r < 0 || r >= HP ||
      c < 0 || c >= WP)
    return 0.f;
  return sims[((size_t)(r * WP + c)) * (SG * SG) + shi * SG + swj];
}

// ---------------- Kernel 2: attention + fused output projection --------------
// r14 structure + pi stored as packed f16 (2 LDS reads/iter instead of 3),
// D9 accumulated in packed halves (__hfma2), pass-2 tc via 4x fdot2.
__global__ __launch_bounds__(512) void attn_kernel(
    const unsigned int* __restrict__ qb16, const unsigned int* __restrict__ kb16,
    const unsigned int* __restrict__ vb16, const float* __restrict__ sims,
    const float* __restrict__ w_proj, float* __restrict__ out) {
  __shared__ __align__(16) unsigned short smK[196 * KSTRU];
  __shared__ __align__(16) unsigned short smV[196 * KSTRU];
  __shared__ __align__(16) unsigned int smpi16[196 * PI_STRU];
  __shared__ __align__(16) unsigned int preLds16[64 * PRE16];
  const int tile = blockIdx.x;
  const int th = tile / 24, tw = tile % 24;
  const int rowBase = th * 8 - 3, colBase = tw * 8 - 3;
  const int tid = threadIdx.x;

  // ---- stage K and V tiles: straight uint4 copies (f16-packed) ----
  for (int i = tid; i < 196 * 8; i += 512) {
    const int loc = i >> 3, c4 = i & 7;
    const int rl = loc / 14, cl = loc - rl * 14;
    const int r = rowBase + rl, c = colBase + cl;
    uint4 k4 = make_uint4(0u, 0u, 0u, 0u);
    uint4 v4 = make_uint4(0u, 0u, 0u, 0u);
    if (r >= 0 && r < HP && c >= 0 && c < WP) {
      const size_t base = (size_t)(r * WP + c) * 32 + (c4 << 2);
      k4 = *(const uint4*)(kb16 + base);
      v4 = *(const uint4*)(vb16 + base);
    }
    *(uint4*)(smK + loc * KSTRU + (c4 << 3)) = k4;
    *(uint4*)(smV + loc * KSTRU + (c4 << 3)) = v4;
  }
  // ---- stage pi table as f16 pairs: [loc][5 uints] (s8 padded) ----
  for (int i = tid; i < 196 * 5; i += 512) {
    const int loc = i / 5, sp = i - loc * 5;
    const int rl = loc / 14, cl = loc - rl * 14;
    const int r = rowBase + rl, c = colBase + cl;
    const int s0 = sp * 2;
    const float v0 = pi_val(sims, th, tw, r, c, s0);
    const float v1 = (s0 + 1 < 9) ? pi_val(sims, th, tw, r, c, s0 + 1) : 0.f;
    smpi16[loc * PI_STRU + sp] = h2pack(v0, v1);
  }
  __syncthreads();

  const int split = tid & 1;
  const int head = (tid >> 1) & 3;
  const int pl = tid >> 3;  // pixel-in-tile 0..63
  const int py = pl >> 3, px = pl & 7;
  const int h = th * 8 + py, w = tw * 8 + px;
  const int pix = h * WP + w;
  int hs = h - 3;
  hs = hs < 0 ? 0 : (hs > HP - 7 ? HP - 7 : hs);
  int wsb = w - 3;
  wsb = wsb < 0 ? 0 : (wsb > WP - 7 ? WP - 7 : wsb);
  const int rl0 = hs - rowBase;   // 0..7
  const int cl0 = wsb - colBase;  // 0..7
  const int hq = head << 4;       // head base in halves
  const int hu = head << 3;       // head base in uints

  const uint4 qa = *(const uint4*)(qb16 + (size_t)pix * 32 + hu);
  const uint4 qc = *(const uint4*)(qb16 + (size_t)pix * 32 + hu + 4);
  const h2 qh0 = ash2(qa.x), qh1 = ash2(qa.y), qh2 = ash2(qa.z),
           qh3 = ash2(qa.w);
  const h2 qh4 = ash2(qc.x), qh5 = ash2(qc.y), qh6 = ash2(qc.z),
           qh7 = ash2(qc.w);

#define DOT8(t, kp)                                           \
  {                                                           \
    const uint4 ka = *(const uint4*)(kp);                     \
    const uint4 kc = *(const uint4*)((kp) + 8);               \
    float t0 = 0.f, t1 = 0.f;                                 \
    t0 = __builtin_amdgcn_fdot2(ash2(ka.x), qh0, t0, false);  \
    t0 = __builtin_amdgcn_fdot2(ash2(ka.y), qh1, t0, false);  \
    t0 = __builtin_amdgcn_fdot2(ash2(ka.z), qh2, t0, false);  \
    t0 = __builtin_amdgcn_fdot2(ash2(ka.w), qh3, t0, false);  \
    t1 = __builtin_amdgcn_fdot2(ash2(kc.x), qh4, t1, false);  \
    t1 = __builtin_amdgcn_fdot2(ash2(kc.y), qh5, t1, false);  \
    t1 = __builtin_amdgcn_fdot2(ash2(kc.z), qh6, t1, false);  \
    t1 = __builtin_amdgcn_fdot2(ash2(kc.w), qh7, t1, false);  \
    t = t0 + t1;                                              \
  }

  // ---- pass 1: partial S, packed D9 ----
  __half2 D9h0 = __float2half2_rn(0.f), D9h1 = __float2half2_rn(0.f);
  __half2 D9h2 = __float2half2_rn(0.f), D9h3 = __float2half2_rn(0.f);
  float D8 = 0.f, S = 0.f;
#pragma unroll 5
  for (int i = 0; i < 25; ++i) {
    const int n = (i << 1) | split;
    if (n < 49) {
      const int kh = (n * 37) >> 8;   // exact n/7 for n<49
      const int kw = n - kh * 7;
      const int loc = (rl0 + kh) * 14 + cl0 + kw;
      float t;
      DOT8(t, smK + loc * KSTRU + hq)
      const float e = exp2f(t);
      S += e;
      const unsigned int* pp = smpi16 + loc * PI_STRU;
      const uint4 pu = *(const uint4*)pp;
      const unsigned int p8u = pp[4];
      const __half2 e2 = __float2half2_rn(e);
      D9h0 = __hfma2(e2, __builtin_bit_cast(__half2, pu.x), D9h0);
      D9h1 = __hfma2(e2, __builtin_bit_cast(__half2, pu.y), D9h1);
      D9h2 = __hfma2(e2, __builtin_bit_cast(__half2, pu.z), D9h2);
      D9h3 = __hfma2(e2, __builtin_bit_cast(__half2, pu.w), D9h3);
      D8 = fmaf(e, (float)ash2(p8u)[0], D8);
    }
  }
  S += __shfl_xor(S, 1);
  D8 += __shfl_xor(D8, 1);
#define COMBH(D)                                                        \
  D = __hadd2(D, __builtin_bit_cast(__half2,                            \
                   __shfl_xor(__builtin_bit_cast(int, D), 1)));
  COMBH(D9h0) COMBH(D9h1) COMBH(D9h2) COMBH(D9h3)
#undef COMBH

  // ---- coef_s = ws[s] / (D[s] + 1e-10*S); packed for pass 2 ----
  h2 ch0, ch1, ch2, ch3;
  float c8;
  {
    const unsigned int* pp =
        smpi16 + ((h - rowBase) * 14 + (w - colBase)) * PI_STRU;
    const uint4 pu = *(const uint4*)pp;
    const unsigned int p8u = pp[4];
    const h2 w0 = ash2(pu.x), w1 = ash2(pu.y), w2 = ash2(pu.z),
             w3 = ash2(pu.w);
    const float epsS = 1e-10f * S;
    ch0[0] = (_Float16)((float)w0[0] / (__low2float(D9h0) + epsS));
    ch0[1] = (_Float16)((float)w0[1] / (__high2float(D9h0) + epsS));
    ch1[0] = (_Float16)((float)w1[0] / (__low2float(D9h1) + epsS));
    ch1[1] = (_Float16)((float)w1[1] / (__high2float(D9h1) + epsS));
    ch2[0] = (_Float16)((float)w2[0] / (__low2float(D9h2) + epsS));
    ch2[1] = (_Float16)((float)w2[1] / (__high2float(D9h2) + epsS));
    ch3[0] = (_Float16)((float)w3[0] / (__low2float(D9h3) + epsS));
    ch3[1] = (_Float16)((float)w3[1] / (__high2float(D9h3) + epsS));
    c8 = (float)ash2(p8u)[0] / (D8 + epsS);
  }

  // ---- pass 2: recompute t,e; tc via fdot2; o += a2 * V(LDS f16) ----
  float4 o0 = make_float4(0.f, 0.f, 0.f, 0.f);
  float4 o1 = make_float4(0.f, 0.f, 0.f, 0.f);
  float4 o2 = make_float4(0.f, 0.f, 0.f, 0.f);
  float4 o3 = make_float4(0.f, 0.f, 0.f, 0.f);
#pragma unroll 5
  for (int i = 0; i < 25; ++i) {
    const int n = (i << 1) | split;
    if (n < 49) {
      const int kh = (n * 37) >> 8;
      const int kw = n - kh * 7;
      const int loc = (rl0 + kh) * 14 + cl0 + kw;
      float t;
      DOT8(t, smK + loc * KSTRU + hq)
      const float e = exp2f(t);
      const unsigned int* pp = smpi16 + loc * PI_STRU;
      const uint4 pu = *(const uint4*)pp;
      const unsigned int p8u = pp[4];
      float tA = __builtin_amdgcn_fdot2(ash2(pu.x), ch0, 0.f, false);
      tA = __builtin_amdgcn_fdot2(ash2(pu.y), ch1, tA, false);
      float tB = __builtin_amdgcn_fdot2(ash2(pu.z), ch2, 0.f, false);
      tB = __builtin_amdgcn_fdot2(ash2(pu.w), ch3, tB, false);
      const float tc = (tA + tB) + c8 * (float)ash2(p8u)[0];
      const float a2 = e * tc;
      const unsigned short* vp = smV + loc * KSTRU + hq;
      const uint4 va = *(const uint4*)vp;
      const uint4 vc = *(const uint4*)(vp + 8);
      const h2 v0 = ash2(va.x), v1 = ash2(va.y), v2 = ash2(va.z),
               v3 = ash2(va.w);
      const h2 v4 = ash2(vc.x), v5 = ash2(vc.y), v6 = ash2(vc.z),
               v7 = ash2(vc.w);
      o0.x = fmaf(a2, (float)v0[0], o0.x);
      o0.y = fmaf(a2, (float)v0[1], o0.y);
      o0.z = fmaf(a2, (float)v1[0], o0.z);
      o0.w = fmaf(a2, (float)v1[1], o0.w);
      o1.x = fmaf(a2, (float)v2[0], o1.x);
      o1.y = fmaf(a2, (float)v2[1], o1.y);
      o1.z = fmaf(a2, (float)v3[0], o1.z);
      o1.w = fmaf(a2, (float)v3[1], o1.w);
      o2.x = fmaf(a2, (float)v4[0], o2.x);
      o2.y = fmaf(a2, (float)v4[1], o2.y);
      o2.z = fmaf(a2, (float)v5[0], o2.z);
      o2.w = fmaf(a2, (float)v5[1], o2.w);
      o3.x = fmaf(a2, (float)v6[0], o3.x);
      o3.y = fmaf(a2, (float)v6[1], o3.y);
      o3.z = fmaf(a2, (float)v7[0], o3.z);
      o3.w = fmaf(a2, (float)v7[1], o3.w);
    }
  }
#undef DOT8

  // ---- combine lane pair; write packed f16 pairs to preLds16 ----
  o0.x += __shfl_xor(o0.x, 1); o0.y += __shfl_xor(o0.y, 1);
  o0.z += __shfl_xor(o0.z, 1); o0.w += __shfl_xor(o0.w, 1);
  o1.x += __shfl_xor(o1.x, 1); o1.y += __shfl_xor(o1.y, 1);
  o1.z += __shfl_xor(o1.z, 1); o1.w += __shfl_xor(o1.w, 1);
  o2.x += __shfl_xor(o2.x, 1); o2.y += __shfl_xor(o2.y, 1);
  o2.z += __shfl_xor(o2.z, 1); o2.w += __shfl_xor(o2.w, 1);
  o3.x += __shfl_xor(o3.x, 1); o3.y += __shfl_xor(o3.y, 1);
  o3.z += __shfl_xor(o3.z, 1); o3.w += __shfl_xor(o3.w, 1);
  {
    unsigned int* pw = preLds16 + pl * PRE16 + (hq >> 1) + split * 4;
    const float4 lo = split ? o2 : o0;
    const float4 hi = split ? o3 : o1;
    pw[0] = h2pack(lo.x, lo.y);
    pw[1] = h2pack(lo.z, lo.w);
    pw[2] = h2pack(hi.x, hi.y);
    pw[3] = h2pack(hi.z, hi.w);
  }
  __syncthreads();

  // ---- fused output projection: 8 groups x 8 cols, w_proj scalar ----------
  const int jb2 = __builtin_amdgcn_readfirstlane(tid >> 6);  // wave-uniform
  const int px2 = tid & 63;
  const int j0 = jb2 * 8;
  const int opix = (th * 8 + (px2 >> 3)) * WP + tw * 8 + (px2 & 7);
  float acc[8];
#pragma unroll
  for (int j = 0; j < 8; ++j) acc[j] = 0.f;
  const unsigned int* prow = preLds16 + px2 * PRE16;
#pragma unroll 8
  for (int cp = 0; cp < 32; ++cp) {
    const h2 hh = ash2(prow[cp]);
    const float xc0 = (float)hh[0];
    const float xc1 = (float)hh[1];
    const float* w0 = w_proj + (2 * cp) * 64 + j0;      // scalar rows
    const float* w1 = w_proj + (2 * cp + 1) * 64 + j0;
#pragma unroll
    for (int j = 0; j < 8; ++j)
      acc[j] = fmaf(xc1, w1[j], fmaf(xc0, w0[j], acc[j]));
  }
#pragma unroll
  for (int j = 0; j < 8; ++j) out[(size_t)(j0 + j) * NPIX + opix] = acc[j];
}

extern "C" void kernel_launch(void* const* d_in, const int* in_sizes, int n_in,
                              void* d_out, int out_size, void* d_ws,
                              size_t ws_size, hipStream_t stream) {
  const float* x = (const float*)d_in[0];
  const float* sims = (const float*)d_in[1];
  const float* w_qk = (const float*)d_in[2];
  const float* w_v = (const float*)d_in[3];
  const float* w_proj = (const float*)d_in[4];
  float* out = (float*)d_out;

  unsigned int* qb16 = (unsigned int*)d_ws;
  unsigned int* kb16 = qb16 + (size_t)NPIX * 32;
  unsigned int* vb16 = kb16 + (size_t)NPIX * 32;

  qkv_kernel<<<dim3(576), 256, 0, stream>>>(x, w_qk, w_v, qb16, kb16, vb16);
  attn_kernel<<<dim3(576), 512, 0, stream>>>(qb16, kb16, vb16, sims, w_proj,
                                             out);
}

// Round 16
// 80.366 us; speedup vs baseline: 1.6683x; 1.6683x over previous
//
#include <hip/hip_runtime.h>
#include <hip/hip_fp16.h>

#define HP 192
#define WP 192
#define NPIX (HP * WP)   // 36864
#define SG 24
#define KSTRU 72         // smK/smV row stride in ushorts (f16): 144 B
#define PI_STRU 12       // smpi16 row stride in uints: 48 B
#define PRE16 33         // preLds16 row stride in uints (f16 pairs)

typedef _Float16 h2 __attribute__((ext_vector_type(2)));

__device__ __forceinline__ unsigned int h2pack(float a, float b) {
  h2 r;
  r[0] = (_Float16)a;
  r[1] = (_Float16)b;
  return __builtin_bit_cast(unsigned int, r);
}
__device__ __forceinline__ h2 ash2(unsigned int u) {
  return __builtin_bit_cast(h2, u);
}

// ---------------- Kernel 1: QKV projection (r14 version: vector loads) -------
// grid (144, 6): jb picks 32 output cols of [q|k|v]. All outputs packed f16
// (q pre-scaled by hd^-0.5*log2(e)). ~29 us measured (r14).
__global__ __launch_bounds__(256) void qkv_kernel(
    const float* __restrict__ x,
    const float* __restrict__ w_qk,
    const float* __restrict__ w_v,
    unsigned int* __restrict__ qb16, unsigned int* __restrict__ kb16,
    unsigned int* __restrict__ vb16) {
  const int jb = blockIdx.y;  // 0..5
  const int pix = blockIdx.x * 256 + threadIdx.x;
  float xv[64];
#pragma unroll
  for (int c = 0; c < 64; ++c) xv[c] = x[c * NPIX + pix];
  float acc[32];
#pragma unroll
  for (int j = 0; j < 32; ++j) acc[j] = 0.f;
  const int j0 = jb * 32;
  if (jb < 4) {
#pragma unroll
    for (int c = 0; c < 64; ++c) {
      const float* wr = w_qk + c * 128 + j0;
      const float xc = xv[c];
#pragma unroll
      for (int j = 0; j < 32; ++j) acc[j] = fmaf(xc, wr[j], acc[j]);
    }
  } else {
#pragma unroll
    for (int c = 0; c < 64; ++c) {
      const float* wr = w_v + c * 64 + (j0 - 128);
      const float xc = xv[c];
#pragma unroll
      for (int j = 0; j < 32; ++j) acc[j] = fmaf(xc, wr[j], acc[j]);
    }
  }
  unsigned int* dst;
  float mul = 1.0f;
  if (jb < 2) {
    dst = qb16 + (size_t)pix * 32 + j0 / 2;
    mul = 0.25f * 1.44269504089f;  // hd^-0.5 * log2(e)
  } else if (jb < 4) {
    dst = kb16 + (size_t)pix * 32 + (j0 - 64) / 2;
  } else {
    dst = vb16 + (size_t)pix * 32 + (j0 - 128) / 2;
  }
#pragma unroll
  for (int j = 0; j < 16; ++j)
    dst[j] = h2pack(acc[2 * j] * mul, acc[2 * j + 1] * mul);
}

__device__ __forceinline__ float pi_val(const float* __restrict__ sims, int th,
                                        int tw, int r, int c, int s) {
  const int dh = s / 3, dw = s - dh * 3;
  const int shi = th + dh - 1, swj = tw + dw - 1;
  if (shi < 0 || shi >= SG || swj < 0 || swj >= SG || r < 0 || r >= HP ||
      c < 0 || c >= WP)
    return 0.f;
  return sims[((size_t)(r * WP + c)) * (SG * SG) + shi * SG + swj];
}

// ---------------- Kernel 2: attention + fused output projection (r15) --------
// Block = 512 = 64 px x 4 heads x 2 splits. K/V/pi in LDS f16; no e[] array
// (pass 2 recomputes); packed-half D9; pass-2 tc via fdot2; proj fused with
// scalar w_proj reads.
__global__ __launch_bounds__(512) void attn_kernel(
    const unsigned int* __restrict__ qb16, const unsigned int* __restrict__ kb16,
    const unsigned int* __restrict__ vb16, const float* __restrict__ sims,
    const float* __restrict__ w_proj, float* __restrict__ out) {
  __shared__ __align__(16) unsigned short smK[196 * KSTRU];
  __shared__ __align__(16) unsigned short smV[196 * KSTRU];
  __shared__ __align__(16) unsigned int smpi16[196 * PI_STRU];
  __shared__ __align__(16) unsigned int preLds16[64 * PRE16];
  const int tile = blockIdx.x;
  const int th = tile / 24, tw = tile % 24;
  const int rowBase = th * 8 - 3, colBase = tw * 8 - 3;
  const int tid = threadIdx.x;

  // ---- stage K and V tiles: straight uint4 copies (f16-packed) ----
  for (int i = tid; i < 196 * 8; i += 512) {
    const int loc = i >> 3, c4 = i & 7;
    const int rl = loc / 14, cl = loc - rl * 14;
    const int r = rowBase + rl, c = colBase + cl;
    uint4 k4 = make_uint4(0u, 0u, 0u, 0u);
    uint4 v4 = make_uint4(0u, 0u, 0u, 0u);
    if (r >= 0 && r < HP && c >= 0 && c < WP) {
      const size_t base = (size_t)(r * WP + c) * 32 + (c4 << 2);
      k4 = *(const uint4*)(kb16 + base);
      v4 = *(const uint4*)(vb16 + base);
    }
    *(uint4*)(smK + loc * KSTRU + (c4 << 3)) = k4;
    *(uint4*)(smV + loc * KSTRU + (c4 << 3)) = v4;
  }
  // ---- stage pi table as f16 pairs: [loc][5 uints] (s8 padded) ----
  for (int i = tid; i < 196 * 5; i += 512) {
    const int loc = i / 5, sp = i - loc * 5;
    const int rl = loc / 14, cl = loc - rl * 14;
    const int r = rowBase + rl, c = colBase + cl;
    const int s0 = sp * 2;
    const float v0 = pi_val(sims, th, tw, r, c, s0);
    const float v1 = (s0 + 1 < 9) ? pi_val(sims, th, tw, r, c, s0 + 1) : 0.f;
    smpi16[loc * PI_STRU + sp] = h2pack(v0, v1);
  }
  __syncthreads();

  const int split = tid & 1;
  const int head = (tid >> 1) & 3;
  const int pl = tid >> 3;  // pixel-in-tile 0..63
  const int py = pl >> 3, px = pl & 7;
  const int h = th * 8 + py, w = tw * 8 + px;
  const int pix = h * WP + w;
  int hs = h - 3;
  hs = hs < 0 ? 0 : (hs > HP - 7 ? HP - 7 : hs);
  int wsb = w - 3;
  wsb = wsb < 0 ? 0 : (wsb > WP - 7 ? WP - 7 : wsb);
  const int rl0 = hs - rowBase;   // 0..7
  const int cl0 = wsb - colBase;  // 0..7
  const int hq = head << 4;       // head base in halves
  const int hu = head << 3;       // head base in uints

  const uint4 qa = *(const uint4*)(qb16 + (size_t)pix * 32 + hu);
  const uint4 qc = *(const uint4*)(qb16 + (size_t)pix * 32 + hu + 4);
  const h2 qh0 = ash2(qa.x), qh1 = ash2(qa.y), qh2 = ash2(qa.z),
           qh3 = ash2(qa.w);
  const h2 qh4 = ash2(qc.x), qh5 = ash2(qc.y), qh6 = ash2(qc.z),
           qh7 = ash2(qc.w);

#define DOT8(t, kp)                                           \
  {                                                           \
    const uint4 ka = *(const uint4*)(kp);                     \
    const uint4 kc = *(const uint4*)((kp) + 8);               \
    float t0 = 0.f, t1 = 0.f;                                 \
    t0 = __builtin_amdgcn_fdot2(ash2(ka.x), qh0, t0, false);  \
    t0 = __builtin_amdgcn_fdot2(ash2(ka.y), qh1, t0, false);  \
    t0 = __builtin_amdgcn_fdot2(ash2(ka.z), qh2, t0, false);  \
    t0 = __builtin_amdgcn_fdot2(ash2(ka.w), qh3, t0, false);  \
    t1 = __builtin_amdgcn_fdot2(ash2(kc.x), qh4, t1, false);  \
    t1 = __builtin_amdgcn_fdot2(ash2(kc.y), qh5, t1, false);  \
    t1 = __builtin_amdgcn_fdot2(ash2(kc.z), qh6, t1, false);  \
    t1 = __builtin_amdgcn_fdot2(ash2(kc.w), qh7, t1, false);  \
    t = t0 + t1;                                              \
  }

  // ---- pass 1: partial S, packed D9 ----
  __half2 D9h0 = __float2half2_rn(0.f), D9h1 = __float2half2_rn(0.f);
  __half2 D9h2 = __float2half2_rn(0.f), D9h3 = __float2half2_rn(0.f);
  float D8 = 0.f, S = 0.f;
#pragma unroll 5
  for (int i = 0; i < 25; ++i) {
    const int n = (i << 1) | split;
    if (n < 49) {
      const int kh = (n * 37) >> 8;   // exact n/7 for n<49
      const int kw = n - kh * 7;
      const int loc = (rl0 + kh) * 14 + cl0 + kw;
      float t;
      DOT8(t, smK + loc * KSTRU + hq)
      const float e = exp2f(t);
      S += e;
      const unsigned int* pp = smpi16 + loc * PI_STRU;
      const uint4 pu = *(const uint4*)pp;
      const unsigned int p8u = pp[4];
      const __half2 e2 = __float2half2_rn(e);
      D9h0 = __hfma2(e2, __builtin_bit_cast(__half2, pu.x), D9h0);
      D9h1 = __hfma2(e2, __builtin_bit_cast(__half2, pu.y), D9h1);
      D9h2 = __hfma2(e2, __builtin_bit_cast(__half2, pu.z), D9h2);
      D9h3 = __hfma2(e2, __builtin_bit_cast(__half2, pu.w), D9h3);
      D8 = fmaf(e, (float)ash2(p8u)[0], D8);
    }
  }
  S += __shfl_xor(S, 1);
  D8 += __shfl_xor(D8, 1);
#define COMBH(D)                                                        \
  D = __hadd2(D, __builtin_bit_cast(__half2,                            \
                   __shfl_xor(__builtin_bit_cast(int, D), 1)));
  COMBH(D9h0) COMBH(D9h1) COMBH(D9h2) COMBH(D9h3)
#undef COMBH

  // ---- coef_s = ws[s] / (D[s] + 1e-10*S); packed for pass 2 ----
  h2 ch0, ch1, ch2, ch3;
  float c8;
  {
    const unsigned int* pp =
        smpi16 + ((h - rowBase) * 14 + (w - colBase)) * PI_STRU;
    const uint4 pu = *(const uint4*)pp;
    const unsigned int p8u = pp[4];
    const h2 w0 = ash2(pu.x), w1 = ash2(pu.y), w2 = ash2(pu.z),
             w3 = ash2(pu.w);
    const float epsS = 1e-10f * S;
    ch0[0] = (_Float16)((float)w0[0] / (__low2float(D9h0) + epsS));
    ch0[1] = (_Float16)((float)w0[1] / (__high2float(D9h0) + epsS));
    ch1[0] = (_Float16)((float)w1[0] / (__low2float(D9h1) + epsS));
    ch1[1] = (_Float16)((float)w1[1] / (__high2float(D9h1) + epsS));
    ch2[0] = (_Float16)((float)w2[0] / (__low2float(D9h2) + epsS));
    ch2[1] = (_Float16)((float)w2[1] / (__high2float(D9h2) + epsS));
    ch3[0] = (_Float16)((float)w3[0] / (__low2float(D9h3) + epsS));
    ch3[1] = (_Float16)((float)w3[1] / (__high2float(D9h3) + epsS));
    c8 = (float)ash2(p8u)[0] / (D8 + epsS);
  }

  // ---- pass 2: recompute t,e; tc via fdot2; o += a2 * V(LDS f16) ----
  float4 o0 = make_float4(0.f, 0.f, 0.f, 0.f);
  float4 o1 = make_float4(0.f, 0.f, 0.f, 0.f);
  float4 o2 = make_float4(0.f, 0.f, 0.f, 0.f);
  float4 o3 = make_float4(0.f, 0.f, 0.f, 0.f);
#pragma unroll 5
  for (int i = 0; i < 25; ++i) {
    const int n = (i << 1) | split;
    if (n < 49) {
      const int kh = (n * 37) >> 8;
      const int kw = n - kh * 7;
      const int loc = (rl0 + kh) * 14 + cl0 + kw;
      float t;
      DOT8(t, smK + loc * KSTRU + hq)
      const float e = exp2f(t);
      const unsigned int* pp = smpi16 + loc * PI_STRU;
      const uint4 pu = *(const uint4*)pp;
      const unsigned int p8u = pp[4];
      float tA = __builtin_amdgcn_fdot2(ash2(pu.x), ch0, 0.f, false);
      tA = __builtin_amdgcn_fdot2(ash2(pu.y), ch1, tA, false);
      float tB = __builtin_amdgcn_fdot2(ash2(pu.z), ch2, 0.f, false);
      tB = __builtin_amdgcn_fdot2(ash2(pu.w), ch3, tB, false);
      const float tc = (tA + tB) + c8 * (float)ash2(p8u)[0];
      const float a2 = e * tc;
      const unsigned short* vp = smV + loc * KSTRU + hq;
      const uint4 va = *(const uint4*)vp;
      const uint4 vc = *(const uint4*)(vp + 8);
      const h2 v0 = ash2(va.x), v1 = ash2(va.y), v2 = ash2(va.z),
               v3 = ash2(va.w);
      const h2 v4 = ash2(vc.x), v5 = ash2(vc.y), v6 = ash2(vc.z),
               v7 = ash2(vc.w);
      o0.x = fmaf(a2, (float)v0[0], o0.x);
      o0.y = fmaf(a2, (float)v0[1], o0.y);
      o0.z = fmaf(a2, (float)v1[0], o0.z);
      o0.w = fmaf(a2, (float)v1[1], o0.w);
      o1.x = fmaf(a2, (float)v2[0], o1.x);
      o1.y = fmaf(a2, (float)v2[1], o1.y);
      o1.z = fmaf(a2, (float)v3[0], o1.z);
      o1.w = fmaf(a2, (float)v3[1], o1.w);
      o2.x = fmaf(a2, (float)v4[0], o2.x);
      o2.y = fmaf(a2, (float)v4[1], o2.y);
      o2.z = fmaf(a2, (float)v5[0], o2.z);
      o2.w = fmaf(a2, (float)v5[1], o2.w);
      o3.x = fmaf(a2, (float)v6[0], o3.x);
      o3.y = fmaf(a2, (float)v6[1], o3.y);
      o3.z = fmaf(a2, (float)v7[0], o3.z);
      o3.w = fmaf(a2, (float)v7[1], o3.w);
    }
  }
#undef DOT8

  // ---- combine lane pair; write packed f16 pairs to preLds16 ----
  o0.x += __shfl_xor(o0.x, 1); o0.y += __shfl_xor(o0.y, 1);
  o0.z += __shfl_xor(o0.z, 1); o0.w += __shfl_xor(o0.w, 1);
  o1.x += __shfl_xor(o1.x, 1); o1.y += __shfl_xor(o1.y, 1);
  o1.z += __shfl_xor(o1.z, 1); o1.w += __shfl_xor(o1.w, 1);
  o2.x += __shfl_xor(o2.x, 1); o2.y += __shfl_xor(o2.y, 1);
  o2.z += __shfl_xor(o2.z, 1); o2.w += __shfl_xor(o2.w, 1);
  o3.x += __shfl_xor(o3.x, 1); o3.y += __shfl_xor(o3.y, 1);
  o3.z += __shfl_xor(o3.z, 1); o3.w += __shfl_xor(o3.w, 1);
  {
    unsigned int* pw = preLds16 + pl * PRE16 + (hq >> 1) + split * 4;
    const float4 lo = split ? o2 : o0;
    const float4 hi = split ? o3 : o1;
    pw[0] = h2pack(lo.x, lo.y);
    pw[1] = h2pack(lo.z, lo.w);
    pw[2] = h2pack(hi.x, hi.y);
    pw[3] = h2pack(hi.z, hi.w);
  }
  __syncthreads();

  // ---- fused output projection: 8 groups x 8 cols, w_proj scalar ----------
  const int jb2 = __builtin_amdgcn_readfirstlane(tid >> 6);  // wave-uniform
  const int px2 = tid & 63;
  const int j0 = jb2 * 8;
  const int opix = (th * 8 + (px2 >> 3)) * WP + tw * 8 + (px2 & 7);
  float acc[8];
#pragma unroll
  for (int j = 0; j < 8; ++j) acc[j] = 0.f;
  const unsigned int* prow = preLds16 + px2 * PRE16;
#pragma unroll 8
  for (int cp = 0; cp < 32; ++cp) {
    const h2 hh = ash2(prow[cp]);
    const float xc0 = (float)hh[0];
    const float xc1 = (float)hh[1];
    const float* w0 = w_proj + (2 * cp) * 64 + j0;      // scalar rows
    const float* w1 = w_proj + (2 * cp + 1) * 64 + j0;
#pragma unroll
    for (int j = 0; j < 8; ++j)
      acc[j] = fmaf(xc1, w1[j], fmaf(xc0, w0[j], acc[j]));
  }
#pragma unroll
  for (int j = 0; j < 8; ++j) out[(size_t)(j0 + j) * NPIX + opix] = acc[j];
}

extern "C" void kernel_launch(void* const* d_in, const int* in_sizes, int n_in,
                              void* d_out, int out_size, void* d_ws,
                              size_t ws_size, hipStream_t stream) {
  const float* x = (const float*)d_in[0];
  const float* sims = (const float*)d_in[1];
  const float* w_qk = (const float*)d_in[2];
  const float* w_v = (const float*)d_in[3];
  const float* w_proj = (const float*)d_in[4];
  float* out = (float*)d_out;

  unsigned int* qb16 = (unsigned int*)d_ws;
  unsigned int* kb16 = qb16 + (size_t)NPIX * 32;
  unsigned int* vb16 = kb16 + (size_t)NPIX * 32;

  qkv_kernel<<<dim3(144, 6), 256, 0, stream>>>(x, w_qk, w_v, qb16, kb16, vb16);
  attn_kernel<<<dim3(576), 512, 0, stream>>>(qb16, kb16, vb16, sims, w_proj,
                                             out);
}

// Round 18
// 76.381 us; speedup vs baseline: 1.7553x; 1.0522x over previous
//
#include <hip/hip_runtime.h>
#include <hip/hip_fp16.h>

#define HP 192
#define WP 192
#define NPIX (HP * WP)   // 36864
#define SG 24
#define KSTRU 72         // smK/smV row stride in ushorts (f16): 144 B
#define PI_STRU 12       // smpi16 row stride in uints: 48 B
#define PRE16 33         // preLds16 row stride in uints (f16 pairs)

typedef _Float16 h2 __attribute__((ext_vector_type(2)));

__device__ __forceinline__ unsigned int h2pack(float a, float b) {
  h2 r;
  r[0] = (_Float16)a;
  r[1] = (_Float16)b;
  return __builtin_bit_cast(unsigned int, r);
}
__device__ __forceinline__ h2 ash2(unsigned int u) {
  return __builtin_bit_cast(h2, u);
}

// ---------------- Kernel 1: QKV projection (jb=12: BW-bound regime) ----------
__global__ __launch_bounds__(256) void qkv_kernel(
    const float* __restrict__ x,
    const float* __restrict__ w_qk,
    const float* __restrict__ w_v,
    unsigned int* __restrict__ qb16, unsigned int* __restrict__ kb16,
    unsigned int* __restrict__ vb16) {
  const int jb = blockIdx.y;  // 0..11
  const int pix = blockIdx.x * 256 + threadIdx.x;
  float xv[64];
#pragma unroll
  for (int c = 0; c < 64; ++c) xv[c] = x[c * NPIX + pix];
  float acc[16];
#pragma unroll
  for (int j = 0; j < 16; ++j) acc[j] = 0.f;
  const int j0 = jb * 16;
  if (jb < 8) {
#pragma unroll
    for (int c = 0; c < 64; ++c) {
      const float* wr = w_qk + c * 128 + j0;
      const float xc = xv[c];
#pragma unroll
      for (int j = 0; j < 16; ++j) acc[j] = fmaf(xc, wr[j], acc[j]);
    }
  } else {
#pragma unroll
    for (int c = 0; c < 64; ++c) {
      const float* wr = w_v + c * 64 + (j0 - 128);
      const float xc = xv[c];
#pragma unroll
      for (int j = 0; j < 16; ++j) acc[j] = fmaf(xc, wr[j], acc[j]);
    }
  }
  unsigned int* dst;
  float mul = 1.0f;
  if (jb < 4) {
    dst = qb16 + (size_t)pix * 32 + j0 / 2;
    mul = 0.25f * 1.44269504089f;  // hd^-0.5 * log2(e)
  } else if (jb < 8) {
    dst = kb16 + (size_t)pix * 32 + (j0 - 64) / 2;
  } else {
    dst = vb16 + (size_t)pix * 32 + (j0 - 128) / 2;
  }
#pragma unroll
  for (int j = 0; j < 8; ++j)
    dst[j] = h2pack(acc[2 * j] * mul, acc[2 * j + 1] * mul);
}

__device__ __forceinline__ float pi_val(const float* __restrict__ sims, int th,
                                        int tw, int r, int c, int s) {
  const int dh = s / 3, dw = s - dh * 3;
  const int shi = th + dh - 1, swj = tw + dw - 1;
  if (shi < 0 || shi >= SG || swj < 0 || swj >= SG || r < 0 || r >= HP ||
      c < 0 || c >= WP)
    return 0.f;
  return sims[((size_t)(r * WP + c)) * (SG * SG) + shi * SG + swj];
}

// ---------------- Kernel 2: attention + fused output projection --------------
// r16 structure + XOR-swizzled K/V chunk layout (write chunk c4^(loc&7), read
// chunk (hc)^(loc&7) -- same involution both sides). preLds index FIXED back
// to head<<3 (r17's head<<2 was the NaN bug).
__global__ __launch_bounds__(512) void attn_kernel(
    const unsigned int* __restrict__ qb16, const unsigned int* __restrict__ kb16,
    const unsigned int* __restrict__ vb16, const float* __restrict__ sims,
    const float* __restrict__ w_proj, float* __restrict__ out) {
  __shared__ __align__(16) unsigned short smK[196 * KSTRU];
  __shared__ __align__(16) unsigned short smV[196 * KSTRU];
  __shared__ __align__(16) unsigned int smpi16[196 * PI_STRU];
  __shared__ __align__(16) unsigned int preLds16[64 * PRE16];
  const int tile = blockIdx.x;
  const int th = tile / 24, tw = tile % 24;
  const int rowBase = th * 8 - 3, colBase = tw * 8 - 3;
  const int tid = threadIdx.x;

  // ---- stage K and V tiles (uint4 copies, chunk XOR-swizzled by loc&7) ----
  for (int i = tid; i < 196 * 8; i += 512) {
    const int loc = i >> 3, c4 = i & 7;
    const int rl = loc / 14, cl = loc - rl * 14;
    const int r = rowBase + rl, c = colBase + cl;
    uint4 k4 = make_uint4(0u, 0u, 0u, 0u);
    uint4 v4 = make_uint4(0u, 0u, 0u, 0u);
    if (r >= 0 && r < HP && c >= 0 && c < WP) {
      const size_t base = (size_t)(r * WP + c) * 32 + (c4 << 2);
      k4 = *(const uint4*)(kb16 + base);
      v4 = *(const uint4*)(vb16 + base);
    }
    const int swc = (c4 ^ (loc & 7)) << 3;  // swizzled chunk (ushort units)
    *(uint4*)(smK + loc * KSTRU + swc) = k4;
    *(uint4*)(smV + loc * KSTRU + swc) = v4;
  }
  // ---- stage pi table as f16 pairs: [loc][5 uints] (s8 padded) ----
  for (int i = tid; i < 196 * 5; i += 512) {
    const int loc = i / 5, sp = i - loc * 5;
    const int rl = loc / 14, cl = loc - rl * 14;
    const int r = rowBase + rl, c = colBase + cl;
    const int s0 = sp * 2;
    const float v0 = pi_val(sims, th, tw, r, c, s0);
    const float v1 = (s0 + 1 < 9) ? pi_val(sims, th, tw, r, c, s0 + 1) : 0.f;
    smpi16[loc * PI_STRU + sp] = h2pack(v0, v1);
  }
  __syncthreads();

  const int split = tid & 1;
  const int head = (tid >> 1) & 3;
  const int pl = tid >> 3;  // pixel-in-tile 0..63
  const int py = pl >> 3, px = pl & 7;
  const int h = th * 8 + py, w = tw * 8 + px;
  const int pix = h * WP + w;
  int hs = h - 3;
  hs = hs < 0 ? 0 : (hs > HP - 7 ? HP - 7 : hs);
  int wsb = w - 3;
  wsb = wsb < 0 ? 0 : (wsb > WP - 7 ? WP - 7 : wsb);
  const int rl0 = hs - rowBase;   // 0..7
  const int cl0 = wsb - colBase;  // 0..7
  const int hc2 = head << 1;      // head chunk base (two 16B chunks per head)
  const int hu = head << 3;       // head base in uints (global q / preLds)

  const uint4 qa = *(const uint4*)(qb16 + (size_t)pix * 32 + hu);
  const uint4 qc = *(const uint4*)(qb16 + (size_t)pix * 32 + hu + 4);
  const h2 qh0 = ash2(qa.x), qh1 = ash2(qa.y), qh2 = ash2(qa.z),
           qh3 = ash2(qa.w);
  const h2 qh4 = ash2(qc.x), qh5 = ash2(qc.y), qh6 = ash2(qc.z),
           qh7 = ash2(qc.w);

// 16-ch dot vs swizzled LDS K row at location LOC
#define DOT8(t, LOC)                                          \
  {                                                           \
    const int sw_ = (LOC) & 7;                                \
    const unsigned short* kb_ = smK + (LOC) * KSTRU;          \
    const uint4 ka = *(const uint4*)(kb_ + ((hc2 ^ sw_) << 3));       \
    const uint4 kc = *(const uint4*)(kb_ + (((hc2 | 1) ^ sw_) << 3)); \
    float t0 = 0.f, t1 = 0.f;                                 \
    t0 = __builtin_amdgcn_fdot2(ash2(ka.x), qh0, t0, false);  \
    t0 = __builtin_amdgcn_fdot2(ash2(ka.y), qh1, t0, false);  \
    t0 = __builtin_amdgcn_fdot2(ash2(ka.z), qh2, t0, false);  \
    t0 = __builtin_amdgcn_fdot2(ash2(ka.w), qh3, t0, false);  \
    t1 = __builtin_amdgcn_fdot2(ash2(kc.x), qh4, t1, false);  \
    t1 = __builtin_amdgcn_fdot2(ash2(kc.y), qh5, t1, false);  \
    t1 = __builtin_amdgcn_fdot2(ash2(kc.z), qh6, t1, false);  \
    t1 = __builtin_amdgcn_fdot2(ash2(kc.w), qh7, t1, false);  \
    t = t0 + t1;                                              \
  }

  // ---- pass 1: partial S, packed D9 ----
  __half2 D9h0 = __float2half2_rn(0.f), D9h1 = __float2half2_rn(0.f);
  __half2 D9h2 = __float2half2_rn(0.f), D9h3 = __float2half2_rn(0.f);
  float D8 = 0.f, S = 0.f;
#pragma unroll 5
  for (int i = 0; i < 25; ++i) {
    const int n = (i << 1) | split;
    if (n < 49) {
      const int kh = (n * 37) >> 8;   // exact n/7 for n<49
      const int kw = n - kh * 7;
      const int loc = (rl0 + kh) * 14 + cl0 + kw;
      float t;
      DOT8(t, loc)
      const float e = exp2f(t);
      S += e;
      const unsigned int* pp = smpi16 + loc * PI_STRU;
      const uint4 pu = *(const uint4*)pp;
      const unsigned int p8u = pp[4];
      const __half2 e2 = __float2half2_rn(e);
      D9h0 = __hfma2(e2, __builtin_bit_cast(__half2, pu.x), D9h0);
      D9h1 = __hfma2(e2, __builtin_bit_cast(__half2, pu.y), D9h1);
      D9h2 = __hfma2(e2, __builtin_bit_cast(__half2, pu.z), D9h2);
      D9h3 = __hfma2(e2, __builtin_bit_cast(__half2, pu.w), D9h3);
      D8 = fmaf(e, (float)ash2(p8u)[0], D8);
    }
  }
  S += __shfl_xor(S, 1);
  D8 += __shfl_xor(D8, 1);
#define COMBH(D)                                                        \
  D = __hadd2(D, __builtin_bit_cast(__half2,                            \
                   __shfl_xor(__builtin_bit_cast(int, D), 1)));
  COMBH(D9h0) COMBH(D9h1) COMBH(D9h2) COMBH(D9h3)
#undef COMBH

  // ---- coef_s = ws[s] / (D[s] + 1e-10*S); packed for pass 2 ----
  h2 ch0, ch1, ch2, ch3;
  float c8;
  {
    const unsigned int* pp =
        smpi16 + ((h - rowBase) * 14 + (w - colBase)) * PI_STRU;
    const uint4 pu = *(const uint4*)pp;
    const unsigned int p8u = pp[4];
    const h2 w0 = ash2(pu.x), w1 = ash2(pu.y), w2 = ash2(pu.z),
             w3 = ash2(pu.w);
    const float epsS = 1e-10f * S;
    ch0[0] = (_Float16)((float)w0[0] / (__low2float(D9h0) + epsS));
    ch0[1] = (_Float16)((float)w0[1] / (__high2float(D9h0) + epsS));
    ch1[0] = (_Float16)((float)w1[0] / (__low2float(D9h1) + epsS));
    ch1[1] = (_Float16)((float)w1[1] / (__high2float(D9h1) + epsS));
    ch2[0] = (_Float16)((float)w2[0] / (__low2float(D9h2) + epsS));
    ch2[1] = (_Float16)((float)w2[1] / (__high2float(D9h2) + epsS));
    ch3[0] = (_Float16)((float)w3[0] / (__low2float(D9h3) + epsS));
    ch3[1] = (_Float16)((float)w3[1] / (__high2float(D9h3) + epsS));
    c8 = (float)ash2(p8u)[0] / (D8 + epsS);
  }

  // ---- pass 2: recompute t,e; tc via fdot2; o += a2 * V(LDS f16) ----
  float4 o0 = make_float4(0.f, 0.f, 0.f, 0.f);
  float4 o1 = make_float4(0.f, 0.f, 0.f, 0.f);
  float4 o2 = make_float4(0.f, 0.f, 0.f, 0.f);
  float4 o3 = make_float4(0.f, 0.f, 0.f, 0.f);
#pragma unroll 5
  for (int i = 0; i < 25; ++i) {
    const int n = (i << 1) | split;
    if (n < 49) {
      const int kh = (n * 37) >> 8;
      const int kw = n - kh * 7;
      const int loc = (rl0 + kh) * 14 + cl0 + kw;
      float t;
      DOT8(t, loc)
      const float e = exp2f(t);
      const unsigned int* pp = smpi16 + loc * PI_STRU;
      const uint4 pu = *(const uint4*)pp;
      const unsigned int p8u = pp[4];
      float tA = __builtin_amdgcn_fdot2(ash2(pu.x), ch0, 0.f, false);
      tA = __builtin_amdgcn_fdot2(ash2(pu.y), ch1, tA, false);
      float tB = __builtin_amdgcn_fdot2(ash2(pu.z), ch2, 0.f, false);
      tB = __builtin_amdgcn_fdot2(ash2(pu.w), ch3, tB, false);
      const float tc = (tA + tB) + c8 * (float)ash2(p8u)[0];
      const float a2 = e * tc;
      const int sw_ = loc & 7;
      const unsigned short* vb_ = smV + loc * KSTRU;
      const uint4 va = *(const uint4*)(vb_ + ((hc2 ^ sw_) << 3));
      const uint4 vc = *(const uint4*)(vb_ + (((hc2 | 1) ^ sw_) << 3));
      const h2 v0 = ash2(va.x), v1 = ash2(va.y), v2 = ash2(va.z),
               v3 = ash2(va.w);
      const h2 v4 = ash2(vc.x), v5 = ash2(vc.y), v6 = ash2(vc.z),
               v7 = ash2(vc.w);
      o0.x = fmaf(a2, (float)v0[0], o0.x);
      o0.y = fmaf(a2, (float)v0[1], o0.y);
      o0.z = fmaf(a2, (float)v1[0], o0.z);
      o0.w = fmaf(a2, (float)v1[1], o0.w);
      o1.x = fmaf(a2, (float)v2[0], o1.x);
      o1.y = fmaf(a2, (float)v2[1], o1.y);
      o1.z = fmaf(a2, (float)v3[0], o1.z);
      o1.w = fmaf(a2, (float)v3[1], o1.w);
      o2.x = fmaf(a2, (float)v4[0], o2.x);
      o2.y = fmaf(a2, (float)v4[1], o2.y);
      o2.z = fmaf(a2, (float)v5[0], o2.z);
      o2.w = fmaf(a2, (float)v5[1], o2.w);
      o3.x = fmaf(a2, (float)v6[0], o3.x);
      o3.y = fmaf(a2, (float)v6[1], o3.y);
      o3.z = fmaf(a2, (float)v7[0], o3.z);
      o3.w = fmaf(a2, (float)v7[1], o3.w);
    }
  }
#undef DOT8

  // ---- combine lane pair; write packed f16 pairs to preLds16 ----
  o0.x += __shfl_xor(o0.x, 1); o0.y += __shfl_xor(o0.y, 1);
  o0.z += __shfl_xor(o0.z, 1); o0.w += __shfl_xor(o0.w, 1);
  o1.x += __shfl_xor(o1.x, 1); o1.y += __shfl_xor(o1.y, 1);
  o1.z += __shfl_xor(o1.z, 1); o1.w += __shfl_xor(o1.w, 1);
  o2.x += __shfl_xor(o2.x, 1); o2.y += __shfl_xor(o2.y, 1);
  o2.z += __shfl_xor(o2.z, 1); o2.w += __shfl_xor(o2.w, 1);
  o3.x += __shfl_xor(o3.x, 1); o3.y += __shfl_xor(o3.y, 1);
  o3.z += __shfl_xor(o3.z, 1); o3.w += __shfl_xor(o3.w, 1);
  {
    // head owns 16 halves = 8 uints -> base = head<<3 (r17 bug: head<<2)
    unsigned int* pw = preLds16 + pl * PRE16 + hu + split * 4;
    const float4 lo = split ? o2 : o0;
    const float4 hi = split ? o3 : o1;
    pw[0] = h2pack(lo.x, lo.y);
    pw[1] = h2pack(lo.z, lo.w);
    pw[2] = h2pack(hi.x, hi.y);
    pw[3] = h2pack(hi.z, hi.w);
  }
  __syncthreads();

  // ---- fused output projection: 8 groups x 8 cols, w_proj scalar ----------
  const int jb2 = __builtin_amdgcn_readfirstlane(tid >> 6);  // wave-uniform
  const int px2 = tid & 63;
  const int j0 = jb2 * 8;
  const int opix = (th * 8 + (px2 >> 3)) * WP + tw * 8 + (px2 & 7);
  float acc[8];
#pragma unroll
  for (int j = 0; j < 8; ++j) acc[j] = 0.f;
  const unsigned int* prow = preLds16 + px2 * PRE16;
#pragma unroll 8
  for (int cp = 0; cp < 32; ++cp) {
    const h2 hh = ash2(prow[cp]);
    const float xc0 = (float)hh[0];
    const float xc1 = (float)hh[1];
    const float* w0 = w_proj + (2 * cp) * 64 + j0;      // scalar rows
    const float* w1 = w_proj + (2 * cp + 1) * 64 + j0;
#pragma unroll
    for (int j = 0; j < 8; ++j)
      acc[j] = fmaf(xc1, w1[j], fmaf(xc0, w0[j], acc[j]));
  }
#pragma unroll
  for (int j = 0; j < 8; ++j) out[(size_t)(j0 + j) * NPIX + opix] = acc[j];
}

extern "C" void kernel_launch(void* const* d_in, const int* in_sizes, int n_in,
                              void* d_out, int out_size, void* d_ws,
                              size_t ws_size, hipStream_t stream) {
  const float* x = (const float*)d_in[0];
  const float* sims = (const float*)d_in[1];
  const float* w_qk = (const float*)d_in[2];
  const float* w_v = (const float*)d_in[3];
  const float* w_proj = (const float*)d_in[4];
  float* out = (float*)d_out;

  unsigned int* qb16 = (unsigned int*)d_ws;
  unsigned int* kb16 = qb16 + (size_t)NPIX * 32;
  unsigned int* vb16 = kb16 + (size_t)NPIX * 32;

  qkv_kernel<<<dim3(144, 12), 256, 0, stream>>>(x, w_qk, w_v, qb16, kb16,
                                                vb16);
  attn_kernel<<<dim3(576), 512, 0, stream>>>(qb16, kb16, vb16, sims, w_proj,
                                             out);
}

// Round 19
// 69.411 us; speedup vs baseline: 1.9316x; 1.1004x over previous
//
#include <hip/hip_runtime.h>
#include <hip/hip_fp16.h>

#define HP 192
#define WP 192
#define NPIX (HP * WP)   // 36864
#define SG 24
#define KSTRU 72         // smK/smV row stride in ushorts (f16): 144 B
#define PI_STRU 12       // smpi16 row stride in uints: 48 B
#define PRE16 33         // preLds16 row stride in uints (f16 pairs)

typedef _Float16 h2 __attribute__((ext_vector_type(2)));

__device__ __forceinline__ unsigned int h2pack(float a, float b) {
  h2 r;
  r[0] = (_Float16)a;
  r[1] = (_Float16)b;
  return __builtin_bit_cast(unsigned int, r);
}
__device__ __forceinline__ h2 ash2(unsigned int u) {
  return __builtin_bit_cast(h2, u);
}
__device__ __forceinline__ __half2 asH2(unsigned int u) {
  return __builtin_bit_cast(__half2, u);
}
__device__ __forceinline__ unsigned int asU(__half2 v) {
  return __builtin_bit_cast(unsigned int, v);
}

// ---------------- Kernel 1: QKV projection (jb=12: BW-bound regime) ----------
__global__ __launch_bounds__(256) void qkv_kernel(
    const float* __restrict__ x,
    const float* __restrict__ w_qk,
    const float* __restrict__ w_v,
    unsigned int* __restrict__ qb16, unsigned int* __restrict__ kb16,
    unsigned int* __restrict__ vb16) {
  const int jb = blockIdx.y;  // 0..11
  const int pix = blockIdx.x * 256 + threadIdx.x;
  float xv[64];
#pragma unroll
  for (int c = 0; c < 64; ++c) xv[c] = x[c * NPIX + pix];
  float acc[16];
#pragma unroll
  for (int j = 0; j < 16; ++j) acc[j] = 0.f;
  const int j0 = jb * 16;
  if (jb < 8) {
#pragma unroll
    for (int c = 0; c < 64; ++c) {
      const float* wr = w_qk + c * 128 + j0;
      const float xc = xv[c];
#pragma unroll
      for (int j = 0; j < 16; ++j) acc[j] = fmaf(xc, wr[j], acc[j]);
    }
  } else {
#pragma unroll
    for (int c = 0; c < 64; ++c) {
      const float* wr = w_v + c * 64 + (j0 - 128);
      const float xc = xv[c];
#pragma unroll
      for (int j = 0; j < 16; ++j) acc[j] = fmaf(xc, wr[j], acc[j]);
    }
  }
  unsigned int* dst;
  float mul = 1.0f;
  if (jb < 4) {
    dst = qb16 + (size_t)pix * 32 + j0 / 2;
    mul = 0.25f * 1.44269504089f;  // hd^-0.5 * log2(e)
  } else if (jb < 8) {
    dst = kb16 + (size_t)pix * 32 + (j0 - 64) / 2;
  } else {
    dst = vb16 + (size_t)pix * 32 + (j0 - 128) / 2;
  }
#pragma unroll
  for (int j = 0; j < 8; ++j)
    dst[j] = h2pack(acc[2 * j] * mul, acc[2 * j + 1] * mul);
}

__device__ __forceinline__ float pi_val(const float* __restrict__ sims, int th,
                                        int tw, int r, int c, int s) {
  const int dh = s / 3, dw = s - dh * 3;
  const int shi = th + dh - 1, swj = tw + dw - 1;
  if (shi < 0 || shi >= SG || swj < 0 || swj >= SG || r < 0 || r >= HP ||
      c < 0 || c >= WP)
    return 0.f;
  return sims[((size_t)(r * WP + c)) * (SG * SG) + shi * SG + swj];
}

// ---------------- Kernel 2: attention + fused output projection --------------
// r16 layout (NO xor swizzle -- the 144B stride's loc*16 term is already an
// additive swizzle; r18 measured the XOR made conflicts 2x worse).
// Loops restructured ROW-WISE: outer kh (7), inner j unrolled with
// kw = 2j+split -> per-row base address computed once, neighbor offsets are
// compile-time ds_read immediates (j*288B for K/V, j*96B for pi).
// o accumulated in packed __half2 (hfma2): V never unpacked.
__global__ __launch_bounds__(512) void attn_kernel(
    const unsigned int* __restrict__ qb16, const unsigned int* __restrict__ kb16,
    const unsigned int* __restrict__ vb16, const float* __restrict__ sims,
    const float* __restrict__ w_proj, float* __restrict__ out) {
  __shared__ __align__(16) unsigned short smK[196 * KSTRU];
  __shared__ __align__(16) unsigned short smV[196 * KSTRU];
  __shared__ __align__(16) unsigned int smpi16[196 * PI_STRU];
  __shared__ __align__(16) unsigned int preLds16[64 * PRE16];
  const int tile = blockIdx.x;
  const int th = tile / 24, tw = tile % 24;
  const int rowBase = th * 8 - 3, colBase = tw * 8 - 3;
  const int tid = threadIdx.x;

  // ---- stage K and V tiles: straight uint4 copies (f16-packed) ----
  for (int i = tid; i < 196 * 8; i += 512) {
    const int loc = i >> 3, c4 = i & 7;
    const int rl = loc / 14, cl = loc - rl * 14;
    const int r = rowBase + rl, c = colBase + cl;
    uint4 k4 = make_uint4(0u, 0u, 0u, 0u);
    uint4 v4 = make_uint4(0u, 0u, 0u, 0u);
    if (r >= 0 && r < HP && c >= 0 && c < WP) {
      const size_t base = (size_t)(r * WP + c) * 32 + (c4 << 2);
      k4 = *(const uint4*)(kb16 + base);
      v4 = *(const uint4*)(vb16 + base);
    }
    *(uint4*)(smK + loc * KSTRU + (c4 << 3)) = k4;
    *(uint4*)(smV + loc * KSTRU + (c4 << 3)) = v4;
  }
  // ---- stage pi table as f16 pairs: [loc][5 uints] (s8 padded) ----
  for (int i = tid; i < 196 * 5; i += 512) {
    const int loc = i / 5, sp = i - loc * 5;
    const int rl = loc / 14, cl = loc - rl * 14;
    const int r = rowBase + rl, c = colBase + cl;
    const int s0 = sp * 2;
    const float v0 = pi_val(sims, th, tw, r, c, s0);
    const float v1 = (s0 + 1 < 9) ? pi_val(sims, th, tw, r, c, s0 + 1) : 0.f;
    smpi16[loc * PI_STRU + sp] = h2pack(v0, v1);
  }
  __syncthreads();

  const int split = tid & 1;
  const int head = (tid >> 1) & 3;
  const int pl = tid >> 3;  // pixel-in-tile 0..63
  const int py = pl >> 3, px = pl & 7;
  const int h = th * 8 + py, w = tw * 8 + px;
  const int pix = h * WP + w;
  int hs = h - 3;
  hs = hs < 0 ? 0 : (hs > HP - 7 ? HP - 7 : hs);
  int wsb = w - 3;
  wsb = wsb < 0 ? 0 : (wsb > WP - 7 ? WP - 7 : wsb);
  const int rl0 = hs - rowBase;   // 0..7
  const int cl0 = wsb - colBase;  // 0..7
  const int hq = head << 4;       // head base in halves
  const int hu = head << 3;       // head base in uints

  const uint4 qa = *(const uint4*)(qb16 + (size_t)pix * 32 + hu);
  const uint4 qc = *(const uint4*)(qb16 + (size_t)pix * 32 + hu + 4);
  const h2 qh0 = ash2(qa.x), qh1 = ash2(qa.y), qh2 = ash2(qa.z),
           qh3 = ash2(qa.w);
  const h2 qh4 = ash2(qc.x), qh5 = ash2(qc.y), qh6 = ash2(qc.z),
           qh7 = ash2(qc.w);

// 16-ch dot vs LDS K row pointer (compile-time offset applied by caller)
#define DOT8P(t, kp)                                          \
  {                                                           \
    const uint4 ka = *(const uint4*)(kp);                     \
    const uint4 kc = *(const uint4*)((kp) + 8);               \
    float t0 = 0.f, t1 = 0.f;                                 \
    t0 = __builtin_amdgcn_fdot2(ash2(ka.x), qh0, t0, false);  \
    t0 = __builtin_amdgcn_fdot2(ash2(ka.y), qh1, t0, false);  \
    t0 = __builtin_amdgcn_fdot2(ash2(ka.z), qh2, t0, false);  \
    t0 = __builtin_amdgcn_fdot2(ash2(ka.w), qh3, t0, false);  \
    t1 = __builtin_amdgcn_fdot2(ash2(kc.x), qh4, t1, false);  \
    t1 = __builtin_amdgcn_fdot2(ash2(kc.y), qh5, t1, false);  \
    t1 = __builtin_amdgcn_fdot2(ash2(kc.z), qh6, t1, false);  \
    t1 = __builtin_amdgcn_fdot2(ash2(kc.w), qh7, t1, false);  \
    t = t0 + t1;                                              \
  }

  // ---- pass 1: rows x (kw = 2j+split) -> partial S, packed D9 ----
  __half2 D9h0 = __float2half2_rn(0.f), D9h1 = __float2half2_rn(0.f);
  __half2 D9h2 = __float2half2_rn(0.f), D9h3 = __float2half2_rn(0.f);
  float D8 = 0.f, S = 0.f;
#pragma unroll 1
  for (int kh = 0; kh < 7; ++kh) {
    const int rowloc = (rl0 + kh) * 14 + cl0 + split;
    const unsigned short* krow = smK + rowloc * KSTRU + hq;
    const unsigned int* prow = smpi16 + rowloc * PI_STRU;
#pragma unroll
    for (int j = 0; j < 4; ++j) {
      if (j < 3 || split == 0) {  // kw = 2j+split must be < 7
        float t;
        DOT8P(t, krow + j * (2 * KSTRU))
        const float e = exp2f(t);
        S += e;
        const unsigned int* pp = prow + j * (2 * PI_STRU);
        const uint4 pu = *(const uint4*)pp;
        const unsigned int p8u = pp[4];
        const __half2 e2 = __float2half2_rn(e);
        D9h0 = __hfma2(e2, asH2(pu.x), D9h0);
        D9h1 = __hfma2(e2, asH2(pu.y), D9h1);
        D9h2 = __hfma2(e2, asH2(pu.z), D9h2);
        D9h3 = __hfma2(e2, asH2(pu.w), D9h3);
        D8 = fmaf(e, (float)ash2(p8u)[0], D8);
      }
    }
  }
  S += __shfl_xor(S, 1);
  D8 += __shfl_xor(D8, 1);
#define COMBH(D) D = __hadd2(D, asH2(__shfl_xor(asU(D), 1)));
  COMBH(D9h0) COMBH(D9h1) COMBH(D9h2) COMBH(D9h3)
#undef COMBH

  // ---- coef_s = ws[s] / (D[s] + 1e-10*S); packed for pass 2 ----
  h2 ch0, ch1, ch2, ch3;
  float c8;
  {
    const unsigned int* pp =
        smpi16 + ((h - rowBase) * 14 + (w - colBase)) * PI_STRU;
    const uint4 pu = *(const uint4*)pp;
    const unsigned int p8u = pp[4];
    const h2 w0 = ash2(pu.x), w1 = ash2(pu.y), w2 = ash2(pu.z),
             w3 = ash2(pu.w);
    const float epsS = 1e-10f * S;
    ch0[0] = (_Float16)((float)w0[0] / (__low2float(D9h0) + epsS));
    ch0[1] = (_Float16)((float)w0[1] / (__high2float(D9h0) + epsS));
    ch1[0] = (_Float16)((float)w1[0] / (__low2float(D9h1) + epsS));
    ch1[1] = (_Float16)((float)w1[1] / (__high2float(D9h1) + epsS));
    ch2[0] = (_Float16)((float)w2[0] / (__low2float(D9h2) + epsS));
    ch2[1] = (_Float16)((float)w2[1] / (__high2float(D9h2) + epsS));
    ch3[0] = (_Float16)((float)w3[0] / (__low2float(D9h3) + epsS));
    ch3[1] = (_Float16)((float)w3[1] / (__high2float(D9h3) + epsS));
    c8 = (float)ash2(p8u)[0] / (D8 + epsS);
  }

  // ---- pass 2: recompute t,e; tc via fdot2; o += a2*V, PACKED half2 ----
  __half2 o0 = __float2half2_rn(0.f), o1 = __float2half2_rn(0.f);
  __half2 o2 = __float2half2_rn(0.f), o3 = __float2half2_rn(0.f);
  __half2 o4 = __float2half2_rn(0.f), o5 = __float2half2_rn(0.f);
  __half2 o6 = __float2half2_rn(0.f), o7 = __float2half2_rn(0.f);
#pragma unroll 1
  for (int kh = 0; kh < 7; ++kh) {
    const int rowloc = (rl0 + kh) * 14 + cl0 + split;
    const unsigned short* krow = smK + rowloc * KSTRU + hq;
    const unsigned short* vrow = smV + rowloc * KSTRU + hq;
    const unsigned int* prow = smpi16 + rowloc * PI_STRU;
#pragma unroll
    for (int j = 0; j < 4; ++j) {
      if (j < 3 || split == 0) {
        float t;
        DOT8P(t, krow + j * (2 * KSTRU))
        const float e = exp2f(t);
        const unsigned int* pp = prow + j * (2 * PI_STRU);
        const uint4 pu = *(const uint4*)pp;
        const unsigned int p8u = pp[4];
        float tA = __builtin_amdgcn_fdot2(ash2(pu.x), ch0, 0.f, false);
        tA = __builtin_amdgcn_fdot2(ash2(pu.y), ch1, tA, false);
        float tB = __builtin_amdgcn_fdot2(ash2(pu.z), ch2, 0.f, false);
        tB = __builtin_amdgcn_fdot2(ash2(pu.w), ch3, tB, false);
        const float tc = (tA + tB) + c8 * (float)ash2(p8u)[0];
        const __half2 a2 = __float2half2_rn(e * tc);
        const unsigned short* vp = vrow + j * (2 * KSTRU);
        const uint4 va = *(const uint4*)vp;
        const uint4 vc = *(const uint4*)(vp + 8);
        o0 = __hfma2(a2, asH2(va.x), o0);
        o1 = __hfma2(a2, asH2(va.y), o1);
        o2 = __hfma2(a2, asH2(va.z), o2);
        o3 = __hfma2(a2, asH2(va.w), o3);
        o4 = __hfma2(a2, asH2(vc.x), o4);
        o5 = __hfma2(a2, asH2(vc.y), o5);
        o6 = __hfma2(a2, asH2(vc.z), o6);
        o7 = __hfma2(a2, asH2(vc.w), o7);
      }
    }
  }
#undef DOT8P

  // ---- combine lane pair (packed); write to preLds16 ----
#define COMBO(x) x = __hadd2(x, asH2(__shfl_xor(asU(x), 1)));
  COMBO(o0) COMBO(o1) COMBO(o2) COMBO(o3)
  COMBO(o4) COMBO(o5) COMBO(o6) COMBO(o7)
#undef COMBO
  {
    unsigned int* pw = preLds16 + pl * PRE16 + hu + split * 4;
    pw[0] = asU(split ? o4 : o0);
    pw[1] = asU(split ? o5 : o1);
    pw[2] = asU(split ? o6 : o2);
    pw[3] = asU(split ? o7 : o3);
  }
  __syncthreads();

  // ---- fused output projection: 8 groups x 8 cols, w_proj scalar ----------
  const int jb2 = __builtin_amdgcn_readfirstlane(tid >> 6);  // wave-uniform
  const int px2 = tid & 63;
  const int j0 = jb2 * 8;
  const int opix = (th * 8 + (px2 >> 3)) * WP + tw * 8 + (px2 & 7);
  float acc[8];
#pragma unroll
  for (int j = 0; j < 8; ++j) acc[j] = 0.f;
  const unsigned int* prow = preLds16 + px2 * PRE16;
#pragma unroll 8
  for (int cp = 0; cp < 32; ++cp) {
    const h2 hh = ash2(prow[cp]);
    const float xc0 = (float)hh[0];
    const float xc1 = (float)hh[1];
    const float* w0 = w_proj + (2 * cp) * 64 + j0;      // scalar rows
    const float* w1 = w_proj + (2 * cp + 1) * 64 + j0;
#pragma unroll
    for (int j = 0; j < 8; ++j)
      acc[j] = fmaf(xc1, w1[j], fmaf(xc0, w0[j], acc[j]));
  }
#pragma unroll
  for (int j = 0; j < 8; ++j) out[(size_t)(j0 + j) * NPIX + opix] = acc[j];
}

extern "C" void kernel_launch(void* const* d_in, const int* in_sizes, int n_in,
                              void* d_out, int out_size, void* d_ws,
                              size_t ws_size, hipStream_t stream) {
  const float* x = (const float*)d_in[0];
  const float* sims = (const float*)d_in[1];
  const float* w_qk = (const float*)d_in[2];
  const float* w_v = (const float*)d_in[3];
  const float* w_proj = (const float*)d_in[4];
  float* out = (float*)d_out;

  unsigned int* qb16 = (unsigned int*)d_ws;
  unsigned int* kb16 = qb16 + (size_t)NPIX * 32;
  unsigned int* vb16 = kb16 + (size_t)NPIX * 32;

  qkv_kernel<<<dim3(144, 12), 256, 0, stream>>>(x, w_qk, w_v, qb16, kb16,
                                                vb16);
  attn_kernel<<<dim3(576), 512, 0, stream>>>(qb16, kb16, vb16, sims, w_proj,
                                             out);
}